// Round 6
// baseline (198.646 us; speedup 1.0000x reference)
//
#include <hip/hip_runtime.h>

// Problem constants (match reference setup_inputs)
#define E_EDGES 1600000
#define N_NODES 50000
#define M_NODES 50000
#define B_BATCH 16

// Binning parameters
#define RB        64                                // dst nodes per bucket
#define KB_BKT    ((M_NODES + RB - 1) / RB)         // 782 buckets
#define NWG_T     ((N_NODES + 255) / 256)           // 196 transpose WGs
#define NWG_B     250                               // binning WGs
#define CHUNK     (E_EDGES / NWG_B)                 // 6400 edges per WG (exact)
#define ITERS     (CHUNK / 256)                     // 25
#define SLOT_CAP  16                                // slots per (bucket,WG) cell; lambda=8.2
#define BK_SLOTS  (NWG_B * SLOT_CAP)                // 4000 slots per bucket
#define SPILL_CAP 256                               // per-WG spill entries
#define PADR      97                                // rowbuf stride (97*8B=776B: conflict-free)
#define ROW_CAP   96                                // max per-row degree (Poisson(32)+11sigma)

// ---------------- Kernel AB: fused transpose + binning ----------------
// WGs [0, NWG_T): transpose x[b][n] -> xt[n][b] (one 64B line per node)
// WGs [NWG_T, ...): bin edges into WG-private cells, one LDS atomic per edge.
// cells layout [k][w][p]: cell (k,w) = 128B owned exclusively by WG w -> lines
// never shared across WGs/XCDs (R5's 65MB write amplification came from [k][p][w]).
__global__ void kAB_bin(const float* __restrict__ x,
                        const int* __restrict__ idx,
                        const float* __restrict__ vals,
                        float4* __restrict__ xt,
                        float2* __restrict__ cells,
                        unsigned* __restrict__ cnt,       // [NWG_B][KB_BKT] coalesced per WG
                        float2* __restrict__ spill,       // [NWG_B][SPILL_CAP]
                        unsigned* __restrict__ spillcnt) {// [NWG_B]
    const int tid = threadIdx.x;
    if (blockIdx.x < NWG_T) {
        int n = blockIdx.x * 256 + tid;
        if (n >= N_NODES) return;
        float v[B_BATCH];
#pragma unroll
        for (int b = 0; b < B_BATCH; ++b) v[b] = x[(size_t)b * N_NODES + n];
        float4* dst = xt + (size_t)n * 4;
#pragma unroll
        for (int j = 0; j < 4; ++j)
            dst[j] = make_float4(v[4*j], v[4*j+1], v[4*j+2], v[4*j+3]);
        return;
    }
    const int w = blockIdx.x - NWG_T;
    __shared__ unsigned cur[KB_BKT];
    __shared__ unsigned scur;
    for (int i = tid; i < KB_BKT; i += 256) cur[i] = 0;
    if (tid == 0) scur = 0;
    __syncthreads();
    const int base = w * CHUNK;
#pragma unroll 4
    for (int it = 0; it < ITERS; ++it) {
        int e = base + it * 256 + tid;
        int s = idx[e];
        int d = idx[E_EDGES + e];
        float v = vals[e];
        int k = d >> 6;
        unsigned pack = (unsigned)s | ((unsigned)(d & 63) << 16); // src:16b | row:6b
        unsigned p = atomicAdd(&cur[k], 1u);                      // rank = slot
        if (p < SLOT_CAP) {
            cells[((size_t)k * NWG_B + w) * SLOT_CAP + p] = make_float2(__uint_as_float(pack), v);
        } else {
            unsigned sp = atomicAdd(&scur, 1u);
            if (sp < SPILL_CAP)
                spill[(size_t)w * SPILL_CAP + sp] =
                    make_float2(__uint_as_float(((unsigned)s << 16) | (unsigned)d), v);
        }
    }
    __syncthreads();
    for (int i = tid; i < KB_BKT; i += 256)
        cnt[(size_t)w * KB_BKT + i] = cur[i];      // coalesced 3KB per WG
    if (tid == 0) spillcnt[w] = (scur <= SPILL_CAP) ? scur : SPILL_CAP;
}

// ---------------- Kernel C: per-bucket row-sort + register accumulate ----------------
__global__ void kC_accum(const float2* __restrict__ cells,
                         const unsigned* __restrict__ cnt,
                         const float2* __restrict__ spill,
                         const unsigned* __restrict__ spillcnt,
                         const float4* __restrict__ xt,
                         const float* __restrict__ bias,
                         float* __restrict__ out) {
    __shared__ float2 rowbuf[RB * PADR];   // 64 x 97 float2 = 49.66 KB
    __shared__ unsigned ccnt[NWG_B];       // clamped per-cell counts
    __shared__ unsigned rcur[RB];
    __shared__ int oflow, sflag;

    const int tid = threadIdx.x;
    const int k = blockIdx.x;
    const int mbase = k * RB;

    if (tid < RB) rcur[tid] = 0;
    if (tid == 0) { oflow = 0; sflag = 0; }
    __syncthreads();

    if (tid < NWG_B) {
        unsigned c = cnt[(size_t)tid * KB_BKT + k];
        ccnt[tid] = (c > SLOT_CAP) ? SLOT_CAP : c;
        if (spillcnt[tid] != 0) sflag = 1;
    }
    __syncthreads();

    // Phase A: contiguous sweep of the bucket's 4000 slots (invalid -> exec-masked),
    // row-scatter into padded row buffer (1 LDS atomic per edge)
    const float2* bkt = cells + (size_t)k * BK_SLOTS;
    for (int s = tid; s < BK_SLOTS; s += 256) {
        int w = s >> 4;             // s / SLOT_CAP
        int p = s & (SLOT_CAP - 1);
        if ((unsigned)p < ccnt[w]) {
            float2 ed = bkt[s];     // coalesced across tid
            unsigned r = (__float_as_uint(ed.x) >> 16) & 63u;
            unsigned q = atomicAdd(&rcur[r], 1u);
            if (q < ROW_CAP) rowbuf[r * PADR + q] = ed;
            else oflow = 1;
        }
    }
    __syncthreads();

    // Spill insertion (rare; deterministic in data)
    if (sflag) {
        for (int i = tid; i < NWG_B * SPILL_CAP; i += 256) {
            int w = i / SPILL_CAP, j = i % SPILL_CAP;
            if ((unsigned)j < spillcnt[w]) {
                float2 sp = spill[(size_t)w * SPILL_CAP + j];
                unsigned u = __float_as_uint(sp.x);
                unsigned d = u & 0xFFFFu;
                if ((int)(d >> 6) == k) {
                    unsigned r = d & 63u;
                    unsigned q = atomicAdd(&rcur[r], 1u);
                    unsigned pk = (u >> 16) | (r << 16);
                    if (q < ROW_CAP) rowbuf[r * PADR + q] = make_float2(__uint_as_float(pk), sp.y);
                    else oflow = 1;
                }
            }
        }
        __syncthreads();
    }

    if (!oflow) {
        // Phase B: thread = (row, quad). Register accumulation, no atomics.
        int r = tid >> 2;
        int quad = tid & 3;
        unsigned nr = rcur[r];                 // <= ROW_CAP (else oflow set)
        const float2* row = &rowbuf[r * PADR];
        float4 acc = make_float4(0.f, 0.f, 0.f, 0.f);
        unsigned j = 0;
        for (; j + 1 < nr; j += 2) {
            float2 a = row[j];
            float2 b = row[j + 1];
            float4 xa = xt[(size_t)(__float_as_uint(a.x) & 0xFFFFu) * 4 + quad];
            float4 xb = xt[(size_t)(__float_as_uint(b.x) & 0xFFFFu) * 4 + quad];
            acc.x += xa.x * a.y; acc.y += xa.y * a.y;
            acc.z += xa.z * a.y; acc.w += xa.w * a.y;
            acc.x += xb.x * b.y; acc.y += xb.y * b.y;
            acc.z += xb.z * b.y; acc.w += xb.w * b.y;
        }
        if (j < nr) {
            float2 a = row[j];
            float4 xa = xt[(size_t)(__float_as_uint(a.x) & 0xFFFFu) * 4 + quad];
            acc.x += xa.x * a.y; acc.y += xa.y * a.y;
            acc.z += xa.z * a.y; acc.w += xa.w * a.y;
        }
        int m = mbase + r;
        if (m < M_NODES) {
            float bv = bias[m];
            out[(size_t)(quad * 4 + 0) * M_NODES + m] = acc.x + bv;
            out[(size_t)(quad * 4 + 1) * M_NODES + m] = acc.y + bv;
            out[(size_t)(quad * 4 + 2) * M_NODES + m] = acc.z + bv;
            out[(size_t)(quad * 4 + 3) * M_NODES + m] = acc.w + bv;
        }
    } else {
        // Fallback: LDS-atomic tile, re-sweeping slots (+spill). Deterministic.
        __syncthreads();
        float* acc = (float*)rowbuf;           // [B_BATCH][RB] = 4 KB
        for (int i = tid; i < B_BATCH * RB; i += 256) acc[i] = 0.f;
        __syncthreads();
        for (int s = tid; s < BK_SLOTS; s += 256) {
            int w = s >> 4;
            int p = s & (SLOT_CAP - 1);
            if ((unsigned)p < ccnt[w]) {
                float2 ed = bkt[s];
                unsigned u = __float_as_uint(ed.x);
                int src = (int)(u & 0xFFFFu);
                int dl = (int)((u >> 16) & 63u);
                float v = ed.y;
                const float4* xr = xt + (size_t)src * 4;
                float4 a = xr[0], b4 = xr[1], c = xr[2], d4 = xr[3];
                float xv[B_BATCH] = {a.x,a.y,a.z,a.w, b4.x,b4.y,b4.z,b4.w,
                                     c.x,c.y,c.z,c.w, d4.x,d4.y,d4.z,d4.w};
#pragma unroll
                for (int b = 0; b < B_BATCH; ++b)
                    atomicAdd(&acc[b * RB + dl], xv[b] * v);
            }
        }
        if (sflag) {
            for (int i = tid; i < NWG_B * SPILL_CAP; i += 256) {
                int w = i / SPILL_CAP, j = i % SPILL_CAP;
                if ((unsigned)j < spillcnt[w]) {
                    float2 sp = spill[(size_t)w * SPILL_CAP + j];
                    unsigned u = __float_as_uint(sp.x);
                    unsigned d = u & 0xFFFFu;
                    if ((int)(d >> 6) == k) {
                        int src = (int)(u >> 16);
                        int dl = (int)(d & 63u);
                        float v = sp.y;
                        const float4* xr = xt + (size_t)src * 4;
                        float4 a = xr[0], b4 = xr[1], c = xr[2], d4 = xr[3];
                        float xv[B_BATCH] = {a.x,a.y,a.z,a.w, b4.x,b4.y,b4.z,b4.w,
                                             c.x,c.y,c.z,c.w, d4.x,d4.y,d4.z,d4.w};
#pragma unroll
                        for (int b = 0; b < B_BATCH; ++b)
                            atomicAdd(&acc[b * RB + dl], xv[b] * v);
                    }
                }
            }
        }
        __syncthreads();
        for (int i = tid; i < B_BATCH * RB; i += 256) {
            int b = i >> 6;
            int dl = i & (RB - 1);
            int m = mbase + dl;
            if (m < M_NODES)
                out[(size_t)b * M_NODES + m] = acc[b * RB + dl] + bias[m];
        }
    }
}

// ---------------- Fallback (round-1) kernels ----------------

__global__ void sl2_init_bias(const float* __restrict__ bias, float* __restrict__ out) {
    int m = blockIdx.x * blockDim.x + threadIdx.x;
    if (m < M_NODES) {
        float bv = bias[m];
#pragma unroll
        for (int b = 0; b < B_BATCH; ++b) out[(size_t)b * M_NODES + m] = bv;
    }
}

__global__ void sl2_edge_scatter(const float* __restrict__ x,
                                 const float* __restrict__ vals,
                                 const int* __restrict__ idx,
                                 float* __restrict__ out) {
    int e = blockIdx.x * blockDim.x + threadIdx.x;
    if (e >= E_EDGES) return;
    int src = idx[e];
    int dst = idx[E_EDGES + e];
    float v = vals[e];
    float xv[B_BATCH];
#pragma unroll
    for (int b = 0; b < B_BATCH; ++b) xv[b] = x[(size_t)b * N_NODES + src];
#pragma unroll
    for (int b = 0; b < B_BATCH; ++b)
        unsafeAtomicAdd(&out[(size_t)b * M_NODES + dst], xv[b] * v);
}

// ---------------- Launch ----------------

extern "C" void kernel_launch(void* const* d_in, const int* in_sizes, int n_in,
                              void* d_out, int out_size, void* d_ws, size_t ws_size,
                              hipStream_t stream) {
    const float* x    = (const float*)d_in[0];  // (B, N, 1)
    const float* vals = (const float*)d_in[1];  // (E,)
    const float* bias = (const float*)d_in[2];  // (M, 1)
    const int*   idx  = (const int*)d_in[3];    // (2, E), row0=src row1=dst
    float* out = (float*)d_out;                 // (B, M, 1)

    const size_t xt_bytes  = (size_t)N_NODES * B_BATCH * sizeof(float);          // 3.2 MB
    const size_t cl_bytes  = (size_t)KB_BKT * BK_SLOTS * sizeof(float2);         // 25.0 MB
    const size_t cnt_bytes = (size_t)NWG_B * KB_BKT * sizeof(unsigned);          // 0.8 MB
    const size_t sp_bytes  = (size_t)NWG_B * SPILL_CAP * sizeof(float2);         // 0.5 MB
    const size_t spc_bytes = (size_t)NWG_B * sizeof(unsigned);
    const size_t need = xt_bytes + cl_bytes + cnt_bytes + sp_bytes + spc_bytes;  // ~29.5 MB

    if (ws_size >= need) {
        char* p = (char*)d_ws;
        float4*   xt    = (float4*)p;    p += xt_bytes;
        float2*   cells = (float2*)p;    p += cl_bytes;
        unsigned* cnt   = (unsigned*)p;  p += cnt_bytes;
        float2*   spill = (float2*)p;    p += sp_bytes;
        unsigned* spc   = (unsigned*)p;

        kAB_bin<<<NWG_T + NWG_B, 256, 0, stream>>>(x, idx, vals, xt, cells, cnt, spill, spc);
        kC_accum<<<KB_BKT, 256, 0, stream>>>(cells, cnt, spill, spc, xt, bias, out);
    } else {
        sl2_init_bias<<<(M_NODES + 255) / 256, 256, 0, stream>>>(bias, out);
        sl2_edge_scatter<<<(E_EDGES + 255) / 256, 256, 0, stream>>>(x, vals, idx, out);
    }
}

// Round 7
// 67.414 us; speedup vs baseline: 2.9467x; 2.9467x over previous
//
#include <hip/hip_runtime.h>

// Problem constants (match reference setup_inputs)
#define E_EDGES 1600000
#define N_NODES 50000
#define M_NODES 50000
#define B_BATCH 16

// Binning parameters
#define RB        64                                // dst nodes per bucket
#define KB_BKT    ((M_NODES + RB - 1) / RB)         // 782 buckets
#define NWG_T     ((N_NODES + 255) / 256)           // 196 transpose WGs
#define NWG_B     250                               // binning WGs
#define CHUNK     (E_EDGES / NWG_B)                 // 6400 edges per WG (exact)
#define ITERS     (CHUNK / 256)                     // 25
#define SLOT_CAP  32                                // slots per (bucket,WG) cell; lambda=8.2
                                                    // P(n>32)=4.5e-11 -> spills NEVER happen
#define BK_SLOTS  (NWG_B * SLOT_CAP)                // 8000 slots per bucket
#define SPILL_CAP 256                               // per-WG spill entries (never used in practice)
#define PADR      97                                // rowbuf stride (97*8B=776B: conflict-free)
#define ROW_CAP   96                                // max per-row degree (Poisson(32)+11sigma)

// ---------------- Kernel AB: fused transpose + binning ----------------
// WGs [0, NWG_T): transpose x[b][n] -> xt[n][b] (one 64B line per node)
// WGs [NWG_T, ...): bin edges into WG-private cells, one LDS atomic per edge.
// cells layout [k][w][p]: cell (k,w) = 256B owned exclusively by WG w -> dirty
// lines never shared across WGs/XCDs (this was R5->R6's kAB 66->18us win).
__global__ void kAB_bin(const float* __restrict__ x,
                        const int* __restrict__ idx,
                        const float* __restrict__ vals,
                        float4* __restrict__ xt,
                        float2* __restrict__ cells,
                        unsigned* __restrict__ cnt,       // [NWG_B][KB_BKT] coalesced per WG
                        float2* __restrict__ spill,       // [NWG_B][SPILL_CAP]
                        unsigned* __restrict__ spillcnt) {// [NWG_B]
    const int tid = threadIdx.x;
    if (blockIdx.x < NWG_T) {
        int n = blockIdx.x * 256 + tid;
        if (n >= N_NODES) return;
        float v[B_BATCH];
#pragma unroll
        for (int b = 0; b < B_BATCH; ++b) v[b] = x[(size_t)b * N_NODES + n];
        float4* dst = xt + (size_t)n * 4;
#pragma unroll
        for (int j = 0; j < 4; ++j)
            dst[j] = make_float4(v[4*j], v[4*j+1], v[4*j+2], v[4*j+3]);
        return;
    }
    const int w = blockIdx.x - NWG_T;
    __shared__ unsigned cur[KB_BKT];
    __shared__ unsigned scur;
    for (int i = tid; i < KB_BKT; i += 256) cur[i] = 0;
    if (tid == 0) scur = 0;
    __syncthreads();
    const int base = w * CHUNK;
#pragma unroll 4
    for (int it = 0; it < ITERS; ++it) {
        int e = base + it * 256 + tid;
        int s = idx[e];
        int d = idx[E_EDGES + e];
        float v = vals[e];
        int k = d >> 6;
        unsigned pack = (unsigned)s | ((unsigned)(d & 63) << 16); // src:16b | row:6b
        unsigned p = atomicAdd(&cur[k], 1u);                      // rank = slot
        if (p < SLOT_CAP) {
            cells[((size_t)k * NWG_B + w) * SLOT_CAP + p] = make_float2(__uint_as_float(pack), v);
        } else {
            unsigned sp = atomicAdd(&scur, 1u);
            if (sp < SPILL_CAP)
                spill[(size_t)w * SPILL_CAP + sp] =
                    make_float2(__uint_as_float(((unsigned)s << 16) | (unsigned)d), v);
        }
    }
    __syncthreads();
    for (int i = tid; i < KB_BKT; i += 256)
        cnt[(size_t)w * KB_BKT + i] = cur[i];      // coalesced 3KB per WG
    if (tid == 0) spillcnt[w] = (scur <= SPILL_CAP) ? scur : SPILL_CAP;
}

// ---------------- Kernel C: per-bucket row-sort + register accumulate ----------------
__global__ void kC_accum(const float2* __restrict__ cells,
                         const unsigned* __restrict__ cnt,
                         const float2* __restrict__ spill,
                         const unsigned* __restrict__ spillcnt,
                         const float4* __restrict__ xt,
                         const float* __restrict__ bias,
                         float* __restrict__ out) {
    __shared__ float2 rowbuf[RB * PADR];   // 64 x 97 float2 = 49.66 KB
    __shared__ unsigned ccnt[NWG_B];       // clamped per-cell counts
    __shared__ unsigned rcur[RB];
    __shared__ int oflow, sflag;

    const int tid = threadIdx.x;
    const int k = blockIdx.x;
    const int mbase = k * RB;

    if (tid < RB) rcur[tid] = 0;
    if (tid == 0) { oflow = 0; sflag = 0; }
    __syncthreads();

    if (tid < NWG_B) {
        unsigned c = cnt[(size_t)tid * KB_BKT + k];
        ccnt[tid] = (c > SLOT_CAP) ? SLOT_CAP : c;
        if (spillcnt[tid] != 0) sflag = 1;   // SLOT_CAP=32 -> never set in practice
    }
    __syncthreads();

    // Phase A: contiguous sweep of the bucket's 8000 slots (invalid -> exec-masked),
    // row-scatter into padded row buffer (1 LDS atomic per edge)
    const float2* bkt = cells + (size_t)k * BK_SLOTS;
    for (int s = tid; s < BK_SLOTS; s += 256) {
        int w = s >> 5;             // s / SLOT_CAP
        int p = s & (SLOT_CAP - 1);
        if ((unsigned)p < ccnt[w]) {
            float2 ed = bkt[s];     // coalesced across tid
            unsigned r = (__float_as_uint(ed.x) >> 16) & 63u;
            unsigned q = atomicAdd(&rcur[r], 1u);
            if (q < ROW_CAP) rowbuf[r * PADR + q] = ed;
            else oflow = 1;
        }
    }
    __syncthreads();

    // Spill insertion (never taken with SLOT_CAP=32; kept for correctness)
    if (sflag) {
        for (int i = tid; i < NWG_B * SPILL_CAP; i += 256) {
            int w = i / SPILL_CAP, j = i % SPILL_CAP;
            if ((unsigned)j < spillcnt[w]) {
                float2 sp = spill[(size_t)w * SPILL_CAP + j];
                unsigned u = __float_as_uint(sp.x);
                unsigned d = u & 0xFFFFu;
                if ((int)(d >> 6) == k) {
                    unsigned r = d & 63u;
                    unsigned q = atomicAdd(&rcur[r], 1u);
                    unsigned pk = (u >> 16) | (r << 16);
                    if (q < ROW_CAP) rowbuf[r * PADR + q] = make_float2(__uint_as_float(pk), sp.y);
                    else oflow = 1;
                }
            }
        }
        __syncthreads();
    }

    if (!oflow) {
        // Phase B: thread = (row, quad). Register accumulation, no atomics.
        int r = tid >> 2;
        int quad = tid & 3;
        unsigned nr = rcur[r];                 // <= ROW_CAP (else oflow set)
        const float2* row = &rowbuf[r * PADR];
        float4 acc = make_float4(0.f, 0.f, 0.f, 0.f);
        unsigned j = 0;
        for (; j + 1 < nr; j += 2) {
            float2 a = row[j];
            float2 b = row[j + 1];
            float4 xa = xt[(size_t)(__float_as_uint(a.x) & 0xFFFFu) * 4 + quad];
            float4 xb = xt[(size_t)(__float_as_uint(b.x) & 0xFFFFu) * 4 + quad];
            acc.x += xa.x * a.y; acc.y += xa.y * a.y;
            acc.z += xa.z * a.y; acc.w += xa.w * a.y;
            acc.x += xb.x * b.y; acc.y += xb.y * b.y;
            acc.z += xb.z * b.y; acc.w += xb.w * b.y;
        }
        if (j < nr) {
            float2 a = row[j];
            float4 xa = xt[(size_t)(__float_as_uint(a.x) & 0xFFFFu) * 4 + quad];
            acc.x += xa.x * a.y; acc.y += xa.y * a.y;
            acc.z += xa.z * a.y; acc.w += xa.w * a.y;
        }
        int m = mbase + r;
        if (m < M_NODES) {
            float bv = bias[m];
            out[(size_t)(quad * 4 + 0) * M_NODES + m] = acc.x + bv;
            out[(size_t)(quad * 4 + 1) * M_NODES + m] = acc.y + bv;
            out[(size_t)(quad * 4 + 2) * M_NODES + m] = acc.z + bv;
            out[(size_t)(quad * 4 + 3) * M_NODES + m] = acc.w + bv;
        }
    } else {
        // Fallback: LDS-atomic tile, re-sweeping slots (+spill). Deterministic.
        __syncthreads();
        float* acc = (float*)rowbuf;           // [B_BATCH][RB] = 4 KB
        for (int i = tid; i < B_BATCH * RB; i += 256) acc[i] = 0.f;
        __syncthreads();
        for (int s = tid; s < BK_SLOTS; s += 256) {
            int w = s >> 5;
            int p = s & (SLOT_CAP - 1);
            if ((unsigned)p < ccnt[w]) {
                float2 ed = bkt[s];
                unsigned u = __float_as_uint(ed.x);
                int src = (int)(u & 0xFFFFu);
                int dl = (int)((u >> 16) & 63u);
                float v = ed.y;
                const float4* xr = xt + (size_t)src * 4;
                float4 a = xr[0], b4 = xr[1], c = xr[2], d4 = xr[3];
                float xv[B_BATCH] = {a.x,a.y,a.z,a.w, b4.x,b4.y,b4.z,b4.w,
                                     c.x,c.y,c.z,c.w, d4.x,d4.y,d4.z,d4.w};
#pragma unroll
                for (int b = 0; b < B_BATCH; ++b)
                    atomicAdd(&acc[b * RB + dl], xv[b] * v);
            }
        }
        if (sflag) {
            for (int i = tid; i < NWG_B * SPILL_CAP; i += 256) {
                int w = i / SPILL_CAP, j = i % SPILL_CAP;
                if ((unsigned)j < spillcnt[w]) {
                    float2 sp = spill[(size_t)w * SPILL_CAP + j];
                    unsigned u = __float_as_uint(sp.x);
                    unsigned d = u & 0xFFFFu;
                    if ((int)(d >> 6) == k) {
                        int src = (int)(u >> 16);
                        int dl = (int)(d & 63u);
                        float v = sp.y;
                        const float4* xr = xt + (size_t)src * 4;
                        float4 a = xr[0], b4 = xr[1], c = xr[2], d4 = xr[3];
                        float xv[B_BATCH] = {a.x,a.y,a.z,a.w, b4.x,b4.y,b4.z,b4.w,
                                             c.x,c.y,c.z,c.w, d4.x,d4.y,d4.z,d4.w};
#pragma unroll
                        for (int b = 0; b < B_BATCH; ++b)
                            atomicAdd(&acc[b * RB + dl], xv[b] * v);
                    }
                }
            }
        }
        __syncthreads();
        for (int i = tid; i < B_BATCH * RB; i += 256) {
            int b = i >> 6;
            int dl = i & (RB - 1);
            int m = mbase + dl;
            if (m < M_NODES)
                out[(size_t)b * M_NODES + m] = acc[b * RB + dl] + bias[m];
        }
    }
}

// ---------------- Fallback (round-1) kernels ----------------

__global__ void sl2_init_bias(const float* __restrict__ bias, float* __restrict__ out) {
    int m = blockIdx.x * blockDim.x + threadIdx.x;
    if (m < M_NODES) {
        float bv = bias[m];
#pragma unroll
        for (int b = 0; b < B_BATCH; ++b) out[(size_t)b * M_NODES + m] = bv;
    }
}

__global__ void sl2_edge_scatter(const float* __restrict__ x,
                                 const float* __restrict__ vals,
                                 const int* __restrict__ idx,
                                 float* __restrict__ out) {
    int e = blockIdx.x * blockDim.x + threadIdx.x;
    if (e >= E_EDGES) return;
    int src = idx[e];
    int dst = idx[E_EDGES + e];
    float v = vals[e];
    float xv[B_BATCH];
#pragma unroll
    for (int b = 0; b < B_BATCH; ++b) xv[b] = x[(size_t)b * N_NODES + src];
#pragma unroll
    for (int b = 0; b < B_BATCH; ++b)
        unsafeAtomicAdd(&out[(size_t)b * M_NODES + dst], xv[b] * v);
}

// ---------------- Launch ----------------

extern "C" void kernel_launch(void* const* d_in, const int* in_sizes, int n_in,
                              void* d_out, int out_size, void* d_ws, size_t ws_size,
                              hipStream_t stream) {
    const float* x    = (const float*)d_in[0];  // (B, N, 1)
    const float* vals = (const float*)d_in[1];  // (E,)
    const float* bias = (const float*)d_in[2];  // (M, 1)
    const int*   idx  = (const int*)d_in[3];    // (2, E), row0=src row1=dst
    float* out = (float*)d_out;                 // (B, M, 1)

    const size_t xt_bytes  = (size_t)N_NODES * B_BATCH * sizeof(float);          // 3.2 MB
    const size_t cl_bytes  = (size_t)KB_BKT * BK_SLOTS * sizeof(float2);         // 50.0 MB
    const size_t cnt_bytes = (size_t)NWG_B * KB_BKT * sizeof(unsigned);          // 0.8 MB
    const size_t sp_bytes  = (size_t)NWG_B * SPILL_CAP * sizeof(float2);         // 0.5 MB
    const size_t spc_bytes = (size_t)NWG_B * sizeof(unsigned);
    const size_t need = xt_bytes + cl_bytes + cnt_bytes + sp_bytes + spc_bytes;  // ~54.6 MB

    if (ws_size >= need) {
        char* p = (char*)d_ws;
        float4*   xt    = (float4*)p;    p += xt_bytes;
        float2*   cells = (float2*)p;    p += cl_bytes;
        unsigned* cnt   = (unsigned*)p;  p += cnt_bytes;
        float2*   spill = (float2*)p;    p += sp_bytes;
        unsigned* spc   = (unsigned*)p;

        kAB_bin<<<NWG_T + NWG_B, 256, 0, stream>>>(x, idx, vals, xt, cells, cnt, spill, spc);
        kC_accum<<<KB_BKT, 256, 0, stream>>>(cells, cnt, spill, spc, xt, bias, out);
    } else {
        sl2_init_bias<<<(M_NODES + 255) / 256, 256, 0, stream>>>(bias, out);
        sl2_edge_scatter<<<(E_EDGES + 255) / 256, 256, 0, stream>>>(x, vals, idx, out);
    }
}

// Round 8
// 64.612 us; speedup vs baseline: 3.0744x; 1.0434x over previous
//
#include <hip/hip_runtime.h>

// Problem constants (match reference setup_inputs)
#define E_EDGES 1600000
#define N_NODES 50000
#define M_NODES 50000
#define B_BATCH 16

// Binning parameters
#define RB         64                               // dst nodes per bucket
#define KB_BKT     782                              // ceil(M/RB) buckets
#define NWG_T      196                              // transpose WGs (ceil(N/256))
#define NWG_B      1024                             // binning WGs -> 4 WG/CU, 16 waves
#define CHUNK      1563                             // ceil(E/NWG_B); last WG ragged
#define BIN_ITERS  7                                // ceil(CHUNK/256)
#define SLOT_CAP   8                                // cell = 64B = one WG-private line
#define BSPILL_CAP 64                               // per-bucket spill entries
#define PADR       73                               // rowbuf stride (73*8B=584B, conflict-free)
#define ROW_CAP    72                               // max row degree (data max ~58-62)

// ---------------- Kernel AB: fused transpose + binning ----------------
// WGs [0, NWG_T): transpose x[b][n] -> xt[n][b]
// WGs [NWG_T, ...): bin edges into WG-private 64B cells [k][w][p<8];
// cell overflow (P~2e-4/cell) -> per-bucket global spill list (rare).
__global__ void kAB_bin(const float* __restrict__ x,
                        const int* __restrict__ idx,
                        const float* __restrict__ vals,
                        float4* __restrict__ xt,
                        float2* __restrict__ cells,
                        unsigned* __restrict__ cnt,      // [NWG_B][KB_BKT] coalesced per WG
                        float2* __restrict__ bspill,     // [KB_BKT][BSPILL_CAP]
                        unsigned* __restrict__ scnt) {   // [KB_BKT], pre-zeroed
    const int tid = threadIdx.x;
    if (blockIdx.x < NWG_T) {
        int n = blockIdx.x * 256 + tid;
        if (n >= N_NODES) return;
        float v[B_BATCH];
#pragma unroll
        for (int b = 0; b < B_BATCH; ++b) v[b] = x[(size_t)b * N_NODES + n];
        float4* dst = xt + (size_t)n * 4;
#pragma unroll
        for (int j = 0; j < 4; ++j)
            dst[j] = make_float4(v[4*j], v[4*j+1], v[4*j+2], v[4*j+3]);
        return;
    }
    const int w = blockIdx.x - NWG_T;
    __shared__ unsigned cur[KB_BKT];
    for (int i = tid; i < KB_BKT; i += 256) cur[i] = 0;
    __syncthreads();
    const int base = w * CHUNK;
    const int end = (base + CHUNK < E_EDGES) ? base + CHUNK : E_EDGES;
#pragma unroll
    for (int it = 0; it < BIN_ITERS; ++it) {
        int e = base + it * 256 + tid;
        if (e < end) {
            int s = idx[e];
            int d = idx[E_EDGES + e];
            float v = vals[e];
            int k = d >> 6;
            unsigned pack = (unsigned)s | ((unsigned)(d & 63) << 16); // src:16b | row:6b
            unsigned p = atomicAdd(&cur[k], 1u);
            if (p < SLOT_CAP) {
                cells[((size_t)k * NWG_B + w) * SLOT_CAP + p] =
                    make_float2(__uint_as_float(pack), v);
            } else {
                unsigned sp = atomicAdd(&scnt[k], 1u);   // global atomic, ~200 total
                if (sp < BSPILL_CAP)
                    bspill[(size_t)k * BSPILL_CAP + sp] =
                        make_float2(__uint_as_float(pack), v);
            }
        }
    }
    __syncthreads();
    for (int i = tid; i < KB_BKT; i += 256)
        cnt[(size_t)w * KB_BKT + i] = cur[i];            // coalesced 3KB per WG
}

// ---------------- Kernel T: transpose cnt [NWG_B][KB_BKT] -> cntT [KB_BKT][NWG_B]
#define TDIM 32
__global__ void kT_cnt(const unsigned* __restrict__ cnt, unsigned* __restrict__ cntT) {
    __shared__ unsigned tile[TDIM][TDIM + 1];
    int kx = blockIdx.x * TDIM;              // k tile base (782)
    int wy = blockIdx.y * TDIM;              // w tile base (1024)
    int tx = threadIdx.x & 31, ty = threadIdx.x >> 5;   // 32x8
    for (int r = ty; r < TDIM; r += 8) {
        int k = kx + tx;
        tile[r][tx] = (k < KB_BKT) ? cnt[(size_t)(wy + r) * KB_BKT + k] : 0u;
    }
    __syncthreads();
    for (int r = ty; r < TDIM; r += 8) {
        int k = kx + r;
        if (k < KB_BKT) cntT[(size_t)k * NWG_B + (wy + tx)] = tile[tx][r];
    }
}

// ---------------- Kernel C: per-bucket row-sort + register accumulate ----------------
__global__ void kC_accum(const float2* __restrict__ cells,
                         const unsigned* __restrict__ cntT,
                         const float2* __restrict__ bspill,
                         const unsigned* __restrict__ scnt,
                         const float4* __restrict__ xt,
                         const float* __restrict__ bias,
                         float* __restrict__ out) {
    __shared__ float2 rowbuf[RB * PADR];   // 64 x 73 float2 = 37.4 KB -> 4 WG/CU
    __shared__ unsigned rcur[RB];
    __shared__ int oflow;
    __shared__ unsigned snum;

    const int tid = threadIdx.x;
    const int k = blockIdx.x;
    const int mbase = k * RB;

    if (tid < RB) rcur[tid] = 0;
    if (tid == 0) { oflow = 0; snum = scnt[k]; }
    __syncthreads();

    // Per-lane cell walk: thread t owns cells w = t, t+256, t+512, t+768.
    // Counts in registers (coalesced loads from cntT); ~8 valid 8B reads/thread.
    unsigned c[4];
#pragma unroll
    for (int m = 0; m < 4; ++m) {
        unsigned cc = cntT[(size_t)k * NWG_B + tid + m * 256];
        c[m] = (cc > SLOT_CAP) ? SLOT_CAP : cc;
    }
#pragma unroll
    for (int m = 0; m < 4; ++m) {
        const float2* cell = cells + ((size_t)k * NWG_B + tid + m * 256) * SLOT_CAP;
        for (unsigned j = 0; j < c[m]; ++j) {
            float2 ed = cell[j];               // lane-private line, sequential
            unsigned r = (__float_as_uint(ed.x) >> 16) & 63u;
            unsigned q = atomicAdd(&rcur[r], 1u);
            if (q < ROW_CAP) rowbuf[r * PADR + q] = ed;
            else oflow = 1;
        }
    }
    __syncthreads();

    // Per-bucket spill insertion (rare, <=64 entries, one iteration)
    if (snum) {
        unsigned ns = (snum > BSPILL_CAP) ? BSPILL_CAP : snum;
        if ((unsigned)tid < ns) {
            float2 ed = bspill[(size_t)k * BSPILL_CAP + tid];
            unsigned r = (__float_as_uint(ed.x) >> 16) & 63u;
            unsigned q = atomicAdd(&rcur[r], 1u);
            if (q < ROW_CAP) rowbuf[r * PADR + q] = ed;
            else oflow = 1;
        }
        __syncthreads();
    }

    if (!oflow) {
        // Phase B: thread = (row, quad). Register accumulation, no atomics.
        int r = tid >> 2;
        int quad = tid & 3;
        unsigned nr = rcur[r];                 // <= ROW_CAP (else oflow set)
        const float2* row = &rowbuf[r * PADR];
        float4 acc = make_float4(0.f, 0.f, 0.f, 0.f);
        unsigned j = 0;
        for (; j + 1 < nr; j += 2) {
            float2 a = row[j];
            float2 b = row[j + 1];
            float4 xa = xt[(size_t)(__float_as_uint(a.x) & 0xFFFFu) * 4 + quad];
            float4 xb = xt[(size_t)(__float_as_uint(b.x) & 0xFFFFu) * 4 + quad];
            acc.x += xa.x * a.y; acc.y += xa.y * a.y;
            acc.z += xa.z * a.y; acc.w += xa.w * a.y;
            acc.x += xb.x * b.y; acc.y += xb.y * b.y;
            acc.z += xb.z * b.y; acc.w += xb.w * b.y;
        }
        if (j < nr) {
            float2 a = row[j];
            float4 xa = xt[(size_t)(__float_as_uint(a.x) & 0xFFFFu) * 4 + quad];
            acc.x += xa.x * a.y; acc.y += xa.y * a.y;
            acc.z += xa.z * a.y; acc.w += xa.w * a.y;
        }
        int m = mbase + r;
        if (m < M_NODES) {
            float bv = bias[m];
            out[(size_t)(quad * 4 + 0) * M_NODES + m] = acc.x + bv;
            out[(size_t)(quad * 4 + 1) * M_NODES + m] = acc.y + bv;
            out[(size_t)(quad * 4 + 2) * M_NODES + m] = acc.z + bv;
            out[(size_t)(quad * 4 + 3) * M_NODES + m] = acc.w + bv;
        }
    } else {
        // Fallback (row>ROW_CAP, not expected for this dataset): LDS-atomic tile.
        __syncthreads();
        float* acc = (float*)rowbuf;           // [B_BATCH][RB] = 4 KB
        for (int i = tid; i < B_BATCH * RB; i += 256) acc[i] = 0.f;
        __syncthreads();
#pragma unroll
        for (int m = 0; m < 4; ++m) {
            const float2* cell = cells + ((size_t)k * NWG_B + tid + m * 256) * SLOT_CAP;
            for (unsigned j = 0; j < c[m]; ++j) {
                float2 ed = cell[j];
                unsigned u = __float_as_uint(ed.x);
                int src = (int)(u & 0xFFFFu);
                int dl = (int)((u >> 16) & 63u);
                float v = ed.y;
                const float4* xr = xt + (size_t)src * 4;
                float4 a = xr[0], b4 = xr[1], cc = xr[2], d4 = xr[3];
                float xv[B_BATCH] = {a.x,a.y,a.z,a.w, b4.x,b4.y,b4.z,b4.w,
                                     cc.x,cc.y,cc.z,cc.w, d4.x,d4.y,d4.z,d4.w};
#pragma unroll
                for (int b = 0; b < B_BATCH; ++b)
                    atomicAdd(&acc[b * RB + dl], xv[b] * v);
            }
        }
        if (snum) {
            unsigned ns = (snum > BSPILL_CAP) ? BSPILL_CAP : snum;
            if ((unsigned)tid < ns) {
                float2 ed = bspill[(size_t)k * BSPILL_CAP + tid];
                unsigned u = __float_as_uint(ed.x);
                int src = (int)(u & 0xFFFFu);
                int dl = (int)((u >> 16) & 63u);
                float v = ed.y;
                const float4* xr = xt + (size_t)src * 4;
                float4 a = xr[0], b4 = xr[1], cc = xr[2], d4 = xr[3];
                float xv[B_BATCH] = {a.x,a.y,a.z,a.w, b4.x,b4.y,b4.z,b4.w,
                                     cc.x,cc.y,cc.z,cc.w, d4.x,d4.y,d4.z,d4.w};
#pragma unroll
                for (int b = 0; b < B_BATCH; ++b)
                    atomicAdd(&acc[b * RB + dl], xv[b] * v);
            }
        }
        __syncthreads();
        for (int i = tid; i < B_BATCH * RB; i += 256) {
            int b = i >> 6;
            int dl = i & (RB - 1);
            int m = mbase + dl;
            if (m < M_NODES)
                out[(size_t)b * M_NODES + m] = acc[b * RB + dl] + bias[m];
        }
    }
}

// ---------------- Fallback (round-1) kernels ----------------

__global__ void sl2_init_bias(const float* __restrict__ bias, float* __restrict__ out) {
    int m = blockIdx.x * blockDim.x + threadIdx.x;
    if (m < M_NODES) {
        float bv = bias[m];
#pragma unroll
        for (int b = 0; b < B_BATCH; ++b) out[(size_t)b * M_NODES + m] = bv;
    }
}

__global__ void sl2_edge_scatter(const float* __restrict__ x,
                                 const float* __restrict__ vals,
                                 const int* __restrict__ idx,
                                 float* __restrict__ out) {
    int e = blockIdx.x * blockDim.x + threadIdx.x;
    if (e >= E_EDGES) return;
    int src = idx[e];
    int dst = idx[E_EDGES + e];
    float v = vals[e];
    float xv[B_BATCH];
#pragma unroll
    for (int b = 0; b < B_BATCH; ++b) xv[b] = x[(size_t)b * N_NODES + src];
#pragma unroll
    for (int b = 0; b < B_BATCH; ++b)
        unsafeAtomicAdd(&out[(size_t)b * M_NODES + dst], xv[b] * v);
}

// ---------------- Launch ----------------

extern "C" void kernel_launch(void* const* d_in, const int* in_sizes, int n_in,
                              void* d_out, int out_size, void* d_ws, size_t ws_size,
                              hipStream_t stream) {
    const float* x    = (const float*)d_in[0];  // (B, N, 1)
    const float* vals = (const float*)d_in[1];  // (E,)
    const float* bias = (const float*)d_in[2];  // (M, 1)
    const int*   idx  = (const int*)d_in[3];    // (2, E), row0=src row1=dst
    float* out = (float*)d_out;                 // (B, M, 1)

    const size_t xt_bytes  = (size_t)N_NODES * B_BATCH * sizeof(float);            // 3.2 MB
    const size_t cl_bytes  = (size_t)KB_BKT * NWG_B * SLOT_CAP * sizeof(float2);   // 51.2 MB
    const size_t cnt_bytes = (size_t)NWG_B * KB_BKT * sizeof(unsigned);            // 3.2 MB
    const size_t cntT_bytes= (size_t)KB_BKT * NWG_B * sizeof(unsigned);            // 3.2 MB
    const size_t sp_bytes  = (size_t)KB_BKT * BSPILL_CAP * sizeof(float2);         // 0.4 MB
    const size_t spc_bytes = (size_t)KB_BKT * sizeof(unsigned);                    // 3.1 KB
    const size_t need = xt_bytes + cl_bytes + cnt_bytes + cntT_bytes + sp_bytes + spc_bytes;

    if (ws_size >= need) {
        char* p = (char*)d_ws;
        float4*   xt    = (float4*)p;    p += xt_bytes;
        float2*   cells = (float2*)p;    p += cl_bytes;
        unsigned* cnt   = (unsigned*)p;  p += cnt_bytes;
        unsigned* cntT  = (unsigned*)p;  p += cntT_bytes;
        float2*   bspill= (float2*)p;    p += sp_bytes;
        unsigned* scnt  = (unsigned*)p;

        hipMemsetAsync(scnt, 0, spc_bytes, stream);
        kAB_bin<<<NWG_T + NWG_B, 256, 0, stream>>>(x, idx, vals, xt, cells, cnt, bspill, scnt);
        dim3 tgrid((KB_BKT + TDIM - 1) / TDIM, NWG_B / TDIM);   // 25 x 32
        kT_cnt<<<tgrid, 256, 0, stream>>>(cnt, cntT);
        kC_accum<<<KB_BKT, 256, 0, stream>>>(cells, cntT, bspill, scnt, xt, bias, out);
    } else {
        sl2_init_bias<<<(M_NODES + 255) / 256, 256, 0, stream>>>(bias, out);
        sl2_edge_scatter<<<(E_EDGES + 255) / 256, 256, 0, stream>>>(x, vals, idx, out);
    }
}

// Round 9
// 62.115 us; speedup vs baseline: 3.1981x; 1.0402x over previous
//
#include <hip/hip_runtime.h>

// Problem constants (match reference setup_inputs)
#define E_EDGES 1600000
#define N_NODES 50000
#define M_NODES 50000
#define B_BATCH 16

// Binning parameters
#define RB         64                               // dst nodes per bucket
#define KB_BKT     782                              // ceil(M/RB) buckets
#define NWG_T      196                              // transpose WGs (ceil(N/256))
#define NWG_B      512                              // binning WGs (~2.8 WG/CU incl transpose)
#define CHUNK      3125                             // E / NWG_B exact (512*3125 = 1.6M)
#define BIN_ITERS  13                               // ceil(CHUNK/256), ragged guard
#define SLOT_CAP   16                               // cell = 128B, lambda = 4.0 -> ~88% line util
#define BSPILL_CAP 64                               // per-bucket spill entries (exp ~0.2 used)
#define PADR       73                               // rowbuf stride (73*8B=584B, conflict-free)
#define ROW_CAP    72                               // max row degree (data max ~58-62)

// ---------------- Kernel AB: fused transpose + binning ----------------
// WGs [0, NWG_T): transpose x[b][n] -> xt[n][b]
// WGs [NWG_T, ...): bin edges into WG-private 128B cells [k][w][p<16];
// cell overflow (P~4e-7/cell) -> per-bucket global spill list.
__global__ void kAB_bin(const float* __restrict__ x,
                        const int* __restrict__ idx,
                        const float* __restrict__ vals,
                        float4* __restrict__ xt,
                        float2* __restrict__ cells,
                        unsigned* __restrict__ cnt,      // [NWG_B][KB_BKT] coalesced per WG
                        float2* __restrict__ bspill,     // [KB_BKT][BSPILL_CAP]
                        unsigned* __restrict__ scnt) {   // [KB_BKT], pre-zeroed
    const int tid = threadIdx.x;
    if (blockIdx.x < NWG_T) {
        int n = blockIdx.x * 256 + tid;
        if (n >= N_NODES) return;
        float v[B_BATCH];
#pragma unroll
        for (int b = 0; b < B_BATCH; ++b) v[b] = x[(size_t)b * N_NODES + n];
        float4* dst = xt + (size_t)n * 4;
#pragma unroll
        for (int j = 0; j < 4; ++j)
            dst[j] = make_float4(v[4*j], v[4*j+1], v[4*j+2], v[4*j+3]);
        return;
    }
    const int w = blockIdx.x - NWG_T;
    __shared__ unsigned cur[KB_BKT];
    for (int i = tid; i < KB_BKT; i += 256) cur[i] = 0;
    __syncthreads();
    const int base = w * CHUNK;
    const int end = base + CHUNK;                    // exact; no global ragged edge
#pragma unroll
    for (int it = 0; it < BIN_ITERS; ++it) {
        int e = base + it * 256 + tid;
        if (e < end) {
            int s = idx[e];
            int d = idx[E_EDGES + e];
            float v = vals[e];
            int k = d >> 6;
            unsigned pack = (unsigned)s | ((unsigned)(d & 63) << 16); // src:16b | row:6b
            unsigned p = atomicAdd(&cur[k], 1u);
            if (p < SLOT_CAP) {
                cells[((size_t)k * NWG_B + w) * SLOT_CAP + p] =
                    make_float2(__uint_as_float(pack), v);
            } else {
                unsigned sp = atomicAdd(&scnt[k], 1u);   // global atomic, ~0 in practice
                if (sp < BSPILL_CAP)
                    bspill[(size_t)k * BSPILL_CAP + sp] =
                        make_float2(__uint_as_float(pack), v);
            }
        }
    }
    __syncthreads();
    for (int i = tid; i < KB_BKT; i += 256)
        cnt[(size_t)w * KB_BKT + i] = cur[i];            // coalesced 3KB per WG
}

// ---------------- Kernel T: transpose cnt [NWG_B][KB_BKT] -> cntT [KB_BKT][NWG_B]
#define TDIM 32
__global__ void kT_cnt(const unsigned* __restrict__ cnt, unsigned* __restrict__ cntT) {
    __shared__ unsigned tile[TDIM][TDIM + 1];
    int kx = blockIdx.x * TDIM;              // k tile base (782)
    int wy = blockIdx.y * TDIM;              // w tile base (512)
    int tx = threadIdx.x & 31, ty = threadIdx.x >> 5;   // 32x8
    for (int r = ty; r < TDIM; r += 8) {
        int k = kx + tx;
        tile[r][tx] = (k < KB_BKT) ? cnt[(size_t)(wy + r) * KB_BKT + k] : 0u;
    }
    __syncthreads();
    for (int r = ty; r < TDIM; r += 8) {
        int k = kx + r;
        if (k < KB_BKT) cntT[(size_t)k * NWG_B + (wy + tx)] = tile[tx][r];
    }
}

// ---------------- Kernel C: per-bucket row-sort + register accumulate ----------------
__global__ void kC_accum(const float2* __restrict__ cells,
                         const unsigned* __restrict__ cntT,
                         const float2* __restrict__ bspill,
                         const unsigned* __restrict__ scnt,
                         const float4* __restrict__ xt,
                         const float* __restrict__ bias,
                         float* __restrict__ out) {
    __shared__ float2 rowbuf[RB * PADR];   // 64 x 73 float2 = 37.4 KB -> 4 WG/CU
    __shared__ unsigned rcur[RB];
    __shared__ int oflow;
    __shared__ unsigned snum;

    const int tid = threadIdx.x;
    const int k = blockIdx.x;
    const int mbase = k * RB;

    if (tid < RB) rcur[tid] = 0;
    if (tid == 0) { oflow = 0; snum = scnt[k]; }
    __syncthreads();

    // Per-lane cell walk: thread t owns cells w = t, t+256.
    // Counts in registers (coalesced loads from cntT); ~8 valid 8B reads/thread,
    // all within the thread's private 128B cell -> line-local sequential reads.
    unsigned c[2];
#pragma unroll
    for (int m = 0; m < 2; ++m) {
        unsigned cc = cntT[(size_t)k * NWG_B + tid + m * 256];
        c[m] = (cc > SLOT_CAP) ? SLOT_CAP : cc;
    }
#pragma unroll
    for (int m = 0; m < 2; ++m) {
        const float2* cell = cells + ((size_t)k * NWG_B + tid + m * 256) * SLOT_CAP;
        for (unsigned j = 0; j < c[m]; ++j) {
            float2 ed = cell[j];
            unsigned r = (__float_as_uint(ed.x) >> 16) & 63u;
            unsigned q = atomicAdd(&rcur[r], 1u);
            if (q < ROW_CAP) rowbuf[r * PADR + q] = ed;
            else oflow = 1;
        }
    }
    __syncthreads();

    // Per-bucket spill insertion (rare, <=64 entries, one iteration)
    if (snum) {
        unsigned ns = (snum > BSPILL_CAP) ? BSPILL_CAP : snum;
        if ((unsigned)tid < ns) {
            float2 ed = bspill[(size_t)k * BSPILL_CAP + tid];
            unsigned r = (__float_as_uint(ed.x) >> 16) & 63u;
            unsigned q = atomicAdd(&rcur[r], 1u);
            if (q < ROW_CAP) rowbuf[r * PADR + q] = ed;
            else oflow = 1;
        }
        __syncthreads();
    }

    if (!oflow) {
        // Phase B: thread = (row, quad). Register accumulation, no atomics.
        int r = tid >> 2;
        int quad = tid & 3;
        unsigned nr = rcur[r];                 // <= ROW_CAP (else oflow set)
        const float2* row = &rowbuf[r * PADR];
        float4 acc = make_float4(0.f, 0.f, 0.f, 0.f);
        unsigned j = 0;
        for (; j + 1 < nr; j += 2) {
            float2 a = row[j];
            float2 b = row[j + 1];
            float4 xa = xt[(size_t)(__float_as_uint(a.x) & 0xFFFFu) * 4 + quad];
            float4 xb = xt[(size_t)(__float_as_uint(b.x) & 0xFFFFu) * 4 + quad];
            acc.x += xa.x * a.y; acc.y += xa.y * a.y;
            acc.z += xa.z * a.y; acc.w += xa.w * a.y;
            acc.x += xb.x * b.y; acc.y += xb.y * b.y;
            acc.z += xb.z * b.y; acc.w += xb.w * b.y;
        }
        if (j < nr) {
            float2 a = row[j];
            float4 xa = xt[(size_t)(__float_as_uint(a.x) & 0xFFFFu) * 4 + quad];
            acc.x += xa.x * a.y; acc.y += xa.y * a.y;
            acc.z += xa.z * a.y; acc.w += xa.w * a.y;
        }
        int m = mbase + r;
        if (m < M_NODES) {
            float bv = bias[m];
            out[(size_t)(quad * 4 + 0) * M_NODES + m] = acc.x + bv;
            out[(size_t)(quad * 4 + 1) * M_NODES + m] = acc.y + bv;
            out[(size_t)(quad * 4 + 2) * M_NODES + m] = acc.z + bv;
            out[(size_t)(quad * 4 + 3) * M_NODES + m] = acc.w + bv;
        }
    } else {
        // Fallback (row > ROW_CAP; not expected for this dataset): LDS-atomic tile.
        __syncthreads();
        float* acc = (float*)rowbuf;           // [B_BATCH][RB] = 4 KB
        for (int i = tid; i < B_BATCH * RB; i += 256) acc[i] = 0.f;
        __syncthreads();
#pragma unroll
        for (int m = 0; m < 2; ++m) {
            const float2* cell = cells + ((size_t)k * NWG_B + tid + m * 256) * SLOT_CAP;
            for (unsigned j = 0; j < c[m]; ++j) {
                float2 ed = cell[j];
                unsigned u = __float_as_uint(ed.x);
                int src = (int)(u & 0xFFFFu);
                int dl = (int)((u >> 16) & 63u);
                float v = ed.y;
                const float4* xr = xt + (size_t)src * 4;
                float4 a = xr[0], b4 = xr[1], cc = xr[2], d4 = xr[3];
                float xv[B_BATCH] = {a.x,a.y,a.z,a.w, b4.x,b4.y,b4.z,b4.w,
                                     cc.x,cc.y,cc.z,cc.w, d4.x,d4.y,d4.z,d4.w};
#pragma unroll
                for (int b = 0; b < B_BATCH; ++b)
                    atomicAdd(&acc[b * RB + dl], xv[b] * v);
            }
        }
        if (snum) {
            unsigned ns = (snum > BSPILL_CAP) ? BSPILL_CAP : snum;
            if ((unsigned)tid < ns) {
                float2 ed = bspill[(size_t)k * BSPILL_CAP + tid];
                unsigned u = __float_as_uint(ed.x);
                int src = (int)(u & 0xFFFFu);
                int dl = (int)((u >> 16) & 63u);
                float v = ed.y;
                const float4* xr = xt + (size_t)src * 4;
                float4 a = xr[0], b4 = xr[1], cc = xr[2], d4 = xr[3];
                float xv[B_BATCH] = {a.x,a.y,a.z,a.w, b4.x,b4.y,b4.z,b4.w,
                                     cc.x,cc.y,cc.z,cc.w, d4.x,d4.y,d4.z,d4.w};
#pragma unroll
                for (int b = 0; b < B_BATCH; ++b)
                    atomicAdd(&acc[b * RB + dl], xv[b] * v);
            }
        }
        __syncthreads();
        for (int i = tid; i < B_BATCH * RB; i += 256) {
            int b = i >> 6;
            int dl = i & (RB - 1);
            int m = mbase + dl;
            if (m < M_NODES)
                out[(size_t)b * M_NODES + m] = acc[b * RB + dl] + bias[m];
        }
    }
}

// ---------------- Fallback (round-1) kernels ----------------

__global__ void sl2_init_bias(const float* __restrict__ bias, float* __restrict__ out) {
    int m = blockIdx.x * blockDim.x + threadIdx.x;
    if (m < M_NODES) {
        float bv = bias[m];
#pragma unroll
        for (int b = 0; b < B_BATCH; ++b) out[(size_t)b * M_NODES + m] = bv;
    }
}

__global__ void sl2_edge_scatter(const float* __restrict__ x,
                                 const float* __restrict__ vals,
                                 const int* __restrict__ idx,
                                 float* __restrict__ out) {
    int e = blockIdx.x * blockDim.x + threadIdx.x;
    if (e >= E_EDGES) return;
    int src = idx[e];
    int dst = idx[E_EDGES + e];
    float v = vals[e];
    float xv[B_BATCH];
#pragma unroll
    for (int b = 0; b < B_BATCH; ++b) xv[b] = x[(size_t)b * N_NODES + src];
#pragma unroll
    for (int b = 0; b < B_BATCH; ++b)
        unsafeAtomicAdd(&out[(size_t)b * M_NODES + dst], xv[b] * v);
}

// ---------------- Launch ----------------

extern "C" void kernel_launch(void* const* d_in, const int* in_sizes, int n_in,
                              void* d_out, int out_size, void* d_ws, size_t ws_size,
                              hipStream_t stream) {
    const float* x    = (const float*)d_in[0];  // (B, N, 1)
    const float* vals = (const float*)d_in[1];  // (E,)
    const float* bias = (const float*)d_in[2];  // (M, 1)
    const int*   idx  = (const int*)d_in[3];    // (2, E), row0=src row1=dst
    float* out = (float*)d_out;                 // (B, M, 1)

    const size_t xt_bytes   = (size_t)N_NODES * B_BATCH * sizeof(float);            // 3.2 MB
    const size_t cl_bytes   = (size_t)KB_BKT * NWG_B * SLOT_CAP * sizeof(float2);   // 51.2 MB
    const size_t cnt_bytes  = (size_t)NWG_B * KB_BKT * sizeof(unsigned);            // 1.6 MB
    const size_t cntT_bytes = (size_t)KB_BKT * NWG_B * sizeof(unsigned);            // 1.6 MB
    const size_t sp_bytes   = (size_t)KB_BKT * BSPILL_CAP * sizeof(float2);         // 0.4 MB
    const size_t spc_bytes  = (size_t)KB_BKT * sizeof(unsigned);                    // 3.1 KB
    const size_t need = xt_bytes + cl_bytes + cnt_bytes + cntT_bytes + sp_bytes + spc_bytes;

    if (ws_size >= need) {
        char* p = (char*)d_ws;
        float4*   xt    = (float4*)p;    p += xt_bytes;
        float2*   cells = (float2*)p;    p += cl_bytes;
        unsigned* cnt   = (unsigned*)p;  p += cnt_bytes;
        unsigned* cntT  = (unsigned*)p;  p += cntT_bytes;
        float2*   bspill= (float2*)p;    p += sp_bytes;
        unsigned* scnt  = (unsigned*)p;

        hipMemsetAsync(scnt, 0, spc_bytes, stream);
        kAB_bin<<<NWG_T + NWG_B, 256, 0, stream>>>(x, idx, vals, xt, cells, cnt, bspill, scnt);
        dim3 tgrid((KB_BKT + TDIM - 1) / TDIM, NWG_B / TDIM);   // 25 x 16
        kT_cnt<<<tgrid, 256, 0, stream>>>(cnt, cntT);
        kC_accum<<<KB_BKT, 256, 0, stream>>>(cells, cntT, bspill, scnt, xt, bias, out);
    } else {
        sl2_init_bias<<<(M_NODES + 255) / 256, 256, 0, stream>>>(bias, out);
        sl2_edge_scatter<<<(E_EDGES + 255) / 256, 256, 0, stream>>>(x, vals, idx, out);
    }
}